// Round 7
// baseline (311.247 us; speedup 1.0000x reference)
//
#include <hip/hip_runtime.h>

#define HIDN 20
#define CHUNK 256
#define WARM 64
#define NB ((CHUNK + WARM) / 64)   // 5 batches of 64 steps
#define WARMB (WARM / 64)          // first batch is warmup

typedef float v2f __attribute__((ext_vector_type(2)));
typedef unsigned long long u64;

__device__ __forceinline__ float bcast(float v, int l) {
    return __int_as_float(__builtin_amdgcn_readlane(__float_as_int(v), l));
}
// broadcast lane l of v into a uniform 64-bit SGPR pair (both words equal).
// readlane -> SGPR, then SALU widen (scalar pipe, free alongside VALU).
__device__ __forceinline__ u64 bpair(float v, int l) {
    unsigned int b = (unsigned int)__builtin_amdgcn_readlane(__float_as_int(v), l);
    return (u64)b | ((u64)b << 32);
}
// acc = w * h + acc as ONE v_pk_fma_f32: weight VGPR pair, h uniform SGPR
// pair (the 1 allowed SGPR operand). Zero v_mov plumbing.
__device__ __forceinline__ void pkfma(v2f& acc, v2f w, u64 h) {
    asm("v_pk_fma_f32 %0, %1, %2, %0" : "+v"(acc) : "v"(w), "s"(h));
}

// gate-split LSTM cell epilogue (f32). Half A lanes hold gate pre-acts (i,f),
// half B lanes hold (g,o) for the same unit.
__device__ __forceinline__ float gate_update(float aA, float aB, float& c,
                                             float cA, float mA, float dA,
                                             bool hB) {
    const float cB = -1.4426950408889634f;
    const float cT =  2.8853900817779268f;
    float eA = __builtin_amdgcn_exp2f(cA * aA);
    float sA = __builtin_amdgcn_rcpf(1.0f + eA);
    float gA = __builtin_fmaf(mA, sA, -dA);          // i (half A) / g (half B)
    float eB = __builtin_amdgcn_exp2f(cB * aB);
    float gB = __builtin_amdgcn_rcpf(1.0f + eB);     // f (half A) / o (half B)
    float oA = __shfl_xor(gA, 32);
    float oB = __shfl_xor(gB, 32);
    float f = hB ? oB : gB;
    float o = hB ? gB : oB;
    c = __builtin_fmaf(f, c, gA * oA);
    float ec = __builtin_amdgcn_exp2f(cT * c);
    float tc = 1.0f - 2.0f * __builtin_amdgcn_rcpf(ec + 1.0f);
    return o * tc;
}

#define RKA(M) M(0) M(1) M(2) M(3) M(4) M(5) M(6) M(7) M(8) M(9)
#define RKB(M) M(10) M(11) M(12) M(13) M(14) M(15) M(16) M(17) M(18) M(19)
#define RK(M) RKA(M) RKB(M)

// One 64-lane wave = one chunk of CHUNK steps (WARM discarded warmup steps).
// Each lane's TWO gate rows (A,B) interleaved as named float2 pairs, consumed
// by inline-asm v_pk_fma_f32 against SGPR-pair broadcasts of h. All f32.
__global__ __launch_bounds__(64)
__attribute__((amdgpu_waves_per_eu(2, 2)))
void lstm_opt_kernel(const float* __restrict__ grad, const float* __restrict__ par,
                     const float* __restrict__ Wih0, const float* __restrict__ Whh0,
                     const float* __restrict__ bih0, const float* __restrict__ bhh0,
                     const float* __restrict__ Wih1, const float* __restrict__ Whh1,
                     const float* __restrict__ bih1, const float* __restrict__ bhh1,
                     const float* __restrict__ Wout, const float* __restrict__ bout,
                     float* __restrict__ out, int n)
{
    const int lane  = threadIdx.x;
    const int lh    = lane & 31;
    const bool hB   = lane >= 32;
    const int u     = (lh < HIDN) ? lh : (HIDN - 1);
    const bool valid = (lh < HIDN);

    const int rowA = (hB ? 2 : 0) * HIDN + u;   // i-row or g-row
    const int rowB = (hB ? 3 : 1) * HIDN + u;   // f-row or o-row

    // ---- paired register weights (named float2 scalars; no arrays) ----
#define DECLW(k) v2f w0_##k, wi_##k, wh_##k;
    RK(DECLW)
#undef DECLW
#define LOADW(k) \
    w0_##k.x = Whh0[rowA * HIDN + k]; w0_##k.y = Whh0[rowB * HIDN + k]; \
    wi_##k.x = Wih1[rowA * HIDN + k]; wi_##k.y = Wih1[rowB * HIDN + k]; \
    wh_##k.x = Whh1[rowA * HIDN + k]; wh_##k.y = Whh1[rowB * HIDN + k];
    RK(LOADW)
#undef LOADW

    v2f wxg, wxp, b0p, b1p;
    wxg.x = Wih0[rowA * 2 + 0]; wxg.y = Wih0[rowB * 2 + 0];
    wxp.x = Wih0[rowA * 2 + 1]; wxp.y = Wih0[rowB * 2 + 1];
    b0p.x = bih0[rowA] + bhh0[rowA]; b0p.y = bih0[rowB] + bhh0[rowB];
    b1p.x = bih1[rowA] + bhh1[rowA]; b1p.y = bih1[rowB] + bhh1[rowB];
    float wo = valid ? Wout[u] : 0.f;
    const float bo = bout[0];

    // ---- pin per-lane constants into VGPRs (defeat remat/sinking) ----
#define PINW(k) asm volatile("" : "+v"(w0_##k), "+v"(wi_##k), "+v"(wh_##k));
    RK(PINW)
#undef PINW
    asm volatile("" : "+v"(wxg), "+v"(wxp), "+v"(b0p), "+v"(b1p), "+v"(wo));

    const float mA = hB ? 2.0f : 1.0f;
    const float dA = hB ? 1.0f : 0.0f;
    const float cA = -1.4426950408889634f * mA;

    float h0 = 0.f, c0 = 0.f, h1 = 0.f, c1 = 0.f;
#define DECLS(k) u64 sh0_##k = 0ull, sh1_##k = 0ull;
    RK(DECLS)
#undef DECLS

    const int t0     = blockIdx.x * CHUNK;
    const int tstart = t0 - WARM;

    float xgv, xpv;
    { int ti = tstart + lane; ti = ti < 0 ? 0 : ti; xgv = grad[ti]; xpv = par[ti]; }

    float rbuf = 0.f;

#pragma unroll 1
    for (int b = 0; b < NB; ++b) {
        float xgn = 0.f, xpn = 0.f;
        if (b + 1 < NB) {
            int ti = tstart + (b + 1) * 64 + lane;
            ti = ti < 0 ? 0 : (ti >= n ? n - 1 : ti);
            xgn = grad[ti]; xpn = par[ti];
        }
        if (b == WARMB && blockIdx.x == 0) {
            // chunk 0: reference's true zero initial state starts exactly here
            h0 = 0.f; c0 = 0.f; h1 = 0.f; c1 = 0.f;
#define ZS(k) sh0_##k = 0ull; sh1_##k = 0ull;
            RK(ZS)
#undef ZS
        }
        const bool main_phase = (b >= WARMB);

#pragma unroll 2
        for (int j = 0; j < 64; ++j) {
            const u64 pxg = bpair(xgv, j);
            const u64 pxp = bpair(xpv, j);

            // ---------------- layer 0 (h0_old broadcasts sh0_*) ----------------
            v2f a = b0p, a2 = {0.f, 0.f};
            pkfma(a, wxg, pxg);
            pkfma(a, wxp, pxp);
#define F0A(k)  pkfma(a,  w0_##k, sh0_##k);
#define F0B(k)  pkfma(a2, w0_##k, sh0_##k);
            RKA(F0A) RKB(F0B)
#undef F0A
#undef F0B
            a += a2;
            h0 = gate_update(a.x, a.y, c0, cA, mA, dA, hB);
#define RD0(k) sh0_##k = bpair(h0, k);
            RK(RD0)
#undef RD0

            // ---------------- layer 1 (h0_new and h1_old) ----------------
            v2f q0 = b1p, q1 = {0.f, 0.f}, q2 = {0.f, 0.f}, q3 = {0.f, 0.f};
#define F1A(k)  pkfma(q0, wi_##k, sh0_##k);
#define F1B(k)  pkfma(q1, wi_##k, sh0_##k);
#define F1C(k)  pkfma(q2, wh_##k, sh1_##k);
#define F1D(k)  pkfma(q3, wh_##k, sh1_##k);
            RKA(F1A) RKB(F1B) RKA(F1C) RKB(F1D)
#undef F1A
#undef F1B
#undef F1C
#undef F1D
            v2f a1 = (q0 + q1) + (q2 + q3);
            h1 = gate_update(a1.x, a1.y, c1, cA, mA, dA, hB);
#define RD1(k) sh1_##k = bpair(h1, k);
            RK(RD1)
#undef RD1

            // ---------------- output head (f32 shfl tree) ----------------
            if (main_phase) {
                float p = h1 * wo;                 // wo==0 on pad lanes
                p += __shfl_xor(p, 16);
                p += __shfl_xor(p, 8);
                p += __shfl_xor(p, 4);
                p += __shfl_xor(p, 2);
                p += __shfl_xor(p, 1);
                rbuf = (lane == j) ? (p + bo) : rbuf;
            }
        }
        if (main_phase) {
            int t = tstart + b * 64 + lane;
            if (t >= 0 && t < n) out[t] = rbuf;    // coalesced, once per 64 steps
        }
        xgv = xgn; xpv = xpn;
    }
}

extern "C" void kernel_launch(void* const* d_in, const int* in_sizes, int n_in,
                              void* d_out, int out_size, void* d_ws, size_t ws_size,
                              hipStream_t stream) {
    const float* grad = (const float*)d_in[0];
    const float* par  = (const float*)d_in[1];
    const float* Wih0 = (const float*)d_in[2];
    const float* Whh0 = (const float*)d_in[3];
    const float* bih0 = (const float*)d_in[4];
    const float* bhh0 = (const float*)d_in[5];
    const float* Wih1 = (const float*)d_in[6];
    const float* Whh1 = (const float*)d_in[7];
    const float* bih1 = (const float*)d_in[8];
    const float* bhh1 = (const float*)d_in[9];
    const float* Wout = (const float*)d_in[10];
    const float* bout = (const float*)d_in[11];
    float* out = (float*)d_out;

    const int n = in_sizes[0];
    const int chunks = (n + CHUNK - 1) / CHUNK;   // 2048 for n=524288 -> 2 waves/SIMD

    lstm_opt_kernel<<<chunks, 64, 0, stream>>>(grad, par, Wih0, Whh0, bih0, bhh0,
                                               Wih1, Whh1, bih1, bhh1, Wout, bout,
                                               out, n);
}

// Round 9
// 272.734 us; speedup vs baseline: 1.1412x; 1.1412x over previous
//
#include <hip/hip_runtime.h>

#define HIDN 20
#define CHUNK 256
#define WARM 64
#define NB ((CHUNK + WARM) / 64)   // 5 batches of 64 steps
#define WARMB (WARM / 64)          // first batch is warmup

typedef float v2f __attribute__((ext_vector_type(2)));

// readlane -> wave-uniform SGPR float (for the scalar x inputs)
__device__ __forceinline__ float bcast(float v, int l) {
    return __int_as_float(__builtin_amdgcn_readlane(__float_as_int(v), l));
}
// full-wave broadcast via ds_bpermute (DS pipe; result is a VGPR usable
// directly as a v_pk_fma_f32 operand half -- no SGPR, no splat movs)
__device__ __forceinline__ float bperm(float v, int srcLane) {
    return __int_as_float(__builtin_amdgcn_ds_bpermute(srcLane << 2, __float_as_int(v)));
}
__device__ __forceinline__ v2f fma2(v2f a, v2f b, v2f c) {
    return __builtin_elementwise_fma(a, b, c);      // -> v_pk_fma_f32 (all-VGPR)
}

// gate-split LSTM cell epilogue (f32). Half A lanes hold gate pre-acts (i,f),
// half B lanes hold (g,o) for the same unit.
__device__ __forceinline__ float gate_update(float aA, float aB, float& c,
                                             float cA, float mA, float dA,
                                             bool hB) {
    const float cB = -1.4426950408889634f;
    const float cT =  2.8853900817779268f;
    float eA = __builtin_amdgcn_exp2f(cA * aA);
    float sA = __builtin_amdgcn_rcpf(1.0f + eA);
    float gA = __builtin_fmaf(mA, sA, -dA);          // i (half A) / g (half B)
    float eB = __builtin_amdgcn_exp2f(cB * aB);
    float gB = __builtin_amdgcn_rcpf(1.0f + eB);     // f (half A) / o (half B)
    float oA = __shfl_xor(gA, 32);
    float oB = __shfl_xor(gB, 32);
    float f = hB ? oB : gB;
    float o = hB ? gB : oB;
    c = __builtin_fmaf(f, c, gA * oA);
    float ec = __builtin_amdgcn_exp2f(cT * c);
    float tc = 1.0f - 2.0f * __builtin_amdgcn_rcpf(ec + 1.0f);
    return o * tc;
}

#define RJA(M) M(0) M(1) M(2) M(3) M(4)
#define RJB(M) M(5) M(6) M(7) M(8) M(9)
#define RJ(M) RJA(M) RJB(M)

// One 64-lane wave = one chunk of CHUNK steps (WARM discarded warmup steps).
// k-axis packing: weight pairs (W[row][2j],W[row][2j+1]) meet broadcast pairs
// (h_2j,h_2j+1) built once per step via ds_bpermute -- v_pk_fma_f32 with zero
// splat plumbing. All f32; arithmetic order per row preserved.
__global__ __launch_bounds__(64)
__attribute__((amdgpu_waves_per_eu(2, 2)))
void lstm_opt_kernel(const float* __restrict__ grad, const float* __restrict__ par,
                     const float* __restrict__ Wih0, const float* __restrict__ Whh0,
                     const float* __restrict__ bih0, const float* __restrict__ bhh0,
                     const float* __restrict__ Wih1, const float* __restrict__ Whh1,
                     const float* __restrict__ bih1, const float* __restrict__ bhh1,
                     const float* __restrict__ Wout, const float* __restrict__ bout,
                     float* __restrict__ out, int n)
{
    const int lane  = threadIdx.x;
    const int lh    = lane & 31;
    const bool hB   = lane >= 32;
    const int u     = (lh < HIDN) ? lh : (HIDN - 1);
    const bool valid = (lh < HIDN);

    const int rowA = (hB ? 2 : 0) * HIDN + u;   // i-row or g-row
    const int rowB = (hB ? 3 : 1) * HIDN + u;   // f-row or o-row

    // ---- k-paired register weights (named v2f scalars; no arrays) ----
#define DECLW(j) v2f w0A_##j, w0B_##j, wiA_##j, wiB_##j, whA_##j, whB_##j;
    RJ(DECLW)
#undef DECLW
#define LOADW(j) \
    w0A_##j.x = Whh0[rowA * HIDN + 2*j]; w0A_##j.y = Whh0[rowA * HIDN + 2*j + 1]; \
    w0B_##j.x = Whh0[rowB * HIDN + 2*j]; w0B_##j.y = Whh0[rowB * HIDN + 2*j + 1]; \
    wiA_##j.x = Wih1[rowA * HIDN + 2*j]; wiA_##j.y = Wih1[rowA * HIDN + 2*j + 1]; \
    wiB_##j.x = Wih1[rowB * HIDN + 2*j]; wiB_##j.y = Wih1[rowB * HIDN + 2*j + 1]; \
    whA_##j.x = Whh1[rowA * HIDN + 2*j]; whA_##j.y = Whh1[rowA * HIDN + 2*j + 1]; \
    whB_##j.x = Whh1[rowB * HIDN + 2*j]; whB_##j.y = Whh1[rowB * HIDN + 2*j + 1];
    RJ(LOADW)
#undef LOADW

    float wxAg = Wih0[rowA * 2 + 0], wxAp = Wih0[rowA * 2 + 1];
    float wxBg = Wih0[rowB * 2 + 0], wxBp = Wih0[rowB * 2 + 1];
    float bA0 = bih0[rowA] + bhh0[rowA];
    float bB0 = bih0[rowB] + bhh0[rowB];
    float bA1 = bih1[rowA] + bhh1[rowA];
    float bB1 = bih1[rowB] + bhh1[rowB];
    float wo = valid ? Wout[u] : 0.f;
    const float bo = bout[0];

    // ---- pin per-lane constants into VGPRs (defeat remat/sinking) ----
#define PINW(j) asm volatile("" : "+v"(w0A_##j), "+v"(w0B_##j), "+v"(wiA_##j), \
                                  "+v"(wiB_##j), "+v"(whA_##j), "+v"(whB_##j));
    RJ(PINW)
#undef PINW
    asm volatile("" : "+v"(wxAg), "+v"(wxAp), "+v"(wxBg), "+v"(wxBp));
    asm volatile("" : "+v"(bA0), "+v"(bB0), "+v"(bA1), "+v"(bB1), "+v"(wo));

    const float mA = hB ? 2.0f : 1.0f;
    const float dA = hB ? 1.0f : 0.0f;
    const float cA = -1.4426950408889634f * mA;

    float h0 = 0.f, c0 = 0.f, h1 = 0.f, c1 = 0.f;
    // persistent broadcast pairs (h_2j, h_2j+1), rebuilt after each h update
#define DECLH(j) v2f hp0_##j = {0.f, 0.f}, hp1_##j = {0.f, 0.f};
    RJ(DECLH)
#undef DECLH

    const int t0     = blockIdx.x * CHUNK;
    const int tstart = t0 - WARM;

    float xgv, xpv;
    { int ti = tstart + lane; ti = ti < 0 ? 0 : ti; xgv = grad[ti]; xpv = par[ti]; }

    float rbuf = 0.f;

#pragma unroll 1
    for (int b = 0; b < NB; ++b) {
        float xgn = 0.f, xpn = 0.f;
        if (b + 1 < NB) {
            int ti = tstart + (b + 1) * 64 + lane;
            ti = ti < 0 ? 0 : (ti >= n ? n - 1 : ti);
            xgn = grad[ti]; xpn = par[ti];
        }
        if (b == WARMB && blockIdx.x == 0) {
            // chunk 0: reference's true zero initial state starts exactly here
            h0 = 0.f; c0 = 0.f; h1 = 0.f; c1 = 0.f;
#define ZH(j) hp0_##j.x = 0.f; hp0_##j.y = 0.f; hp1_##j.x = 0.f; hp1_##j.y = 0.f;
            RJ(ZH)
#undef ZH
        }
        const bool main_phase = (b >= WARMB);

#pragma unroll 2
        for (int j = 0; j < 64; ++j) {
            const float xg = bcast(xgv, j);
            const float xp = bcast(xpv, j);

            // ---------------- layer 0 (h0_old pairs hp0_*) ----------------
            v2f aA = {0.f, 0.f}, aB = {0.f, 0.f}, aA2 = {0.f, 0.f}, aB2 = {0.f, 0.f};
#define F0A(j_) aA  = fma2(w0A_##j_, hp0_##j_, aA);  aB  = fma2(w0B_##j_, hp0_##j_, aB);
#define F0B(j_) aA2 = fma2(w0A_##j_, hp0_##j_, aA2); aB2 = fma2(w0B_##j_, hp0_##j_, aB2);
            RJA(F0A) RJB(F0B)
#undef F0A
#undef F0B
            const float xpA = __builtin_fmaf(wxAp, xp, __builtin_fmaf(wxAg, xg, bA0));
            const float xpB = __builtin_fmaf(wxBp, xp, __builtin_fmaf(wxBg, xg, bB0));
            const float a0A = ((aA.x + aA.y) + (aA2.x + aA2.y)) + xpA;
            const float a0B = ((aB.x + aB.y) + (aB2.x + aB2.y)) + xpB;
            h0 = gate_update(a0A, a0B, c0, cA, mA, dA, hB);

            // rebuild h0 pairs (serve layer 1 now and layer 0 next step)
#define RB0(j_) hp0_##j_.x = bperm(h0, 2*j_); hp0_##j_.y = bperm(h0, 2*j_ + 1);
            RJ(RB0)
#undef RB0

            // ---------------- layer 1 (h0_new pairs, h1_old pairs) ----------------
            v2f qA = {0.f, 0.f}, qB = {0.f, 0.f}, qA2 = {0.f, 0.f}, qB2 = {0.f, 0.f};
#define F1A(j_) qA  = fma2(wiA_##j_, hp0_##j_, qA);  qB  = fma2(wiB_##j_, hp0_##j_, qB);
#define F1B(j_) qA2 = fma2(whA_##j_, hp1_##j_, qA2); qB2 = fma2(whB_##j_, hp1_##j_, qB2);
            RJ(F1A) RJ(F1B)
#undef F1A
#undef F1B
            const float a1A = ((qA.x + qA.y) + (qA2.x + qA2.y)) + bA1;
            const float a1B = ((qB.x + qB.y) + (qB2.x + qB2.y)) + bB1;
            h1 = gate_update(a1A, a1B, c1, cA, mA, dA, hB);

            // rebuild h1 pairs (serve layer 1 next step)
#define RB1(j_) hp1_##j_.x = bperm(h1, 2*j_); hp1_##j_.y = bperm(h1, 2*j_ + 1);
            RJ(RB1)
#undef RB1

            // ---------------- output head (f32 shfl tree) ----------------
            if (main_phase) {
                float p = h1 * wo;                 // wo==0 on pad lanes
                p += __shfl_xor(p, 16);
                p += __shfl_xor(p, 8);
                p += __shfl_xor(p, 4);
                p += __shfl_xor(p, 2);
                p += __shfl_xor(p, 1);
                rbuf = (lane == j) ? (p + bo) : rbuf;
            }
        }
        if (main_phase) {
            int t = tstart + b * 64 + lane;
            if (t >= 0 && t < n) out[t] = rbuf;    // coalesced, once per 64 steps
        }
        xgv = xgn; xpv = xpn;
    }
}

extern "C" void kernel_launch(void* const* d_in, const int* in_sizes, int n_in,
                              void* d_out, int out_size, void* d_ws, size_t ws_size,
                              hipStream_t stream) {
    const float* grad = (const float*)d_in[0];
    const float* par  = (const float*)d_in[1];
    const float* Wih0 = (const float*)d_in[2];
    const float* Whh0 = (const float*)d_in[3];
    const float* bih0 = (const float*)d_in[4];
    const float* bhh0 = (const float*)d_in[5];
    const float* Wih1 = (const float*)d_in[6];
    const float* Whh1 = (const float*)d_in[7];
    const float* bih1 = (const float*)d_in[8];
    const float* bhh1 = (const float*)d_in[9];
    const float* Wout = (const float*)d_in[10];
    const float* bout = (const float*)d_in[11];
    float* out = (float*)d_out;

    const int n = in_sizes[0];
    const int chunks = (n + CHUNK - 1) / CHUNK;   // 2048 for n=524288 -> 2 waves/SIMD

    lstm_opt_kernel<<<chunks, 64, 0, stream>>>(grad, par, Wih0, Whh0, bih0, bhh0,
                                               Wih1, Whh1, bih1, bhh1, Wout, bout,
                                               out, n);
}